// Round 12
// baseline (1017.332 us; speedup 1.0000x reference)
//
#include <hip/hip_runtime.h>
#include <math.h>

static constexpr int H = 496, W = 432, Bn = 2, Np = 16000;
static constexpr int HW = H * W;  // 214272

typedef __bf16 bf16x8 __attribute__((ext_vector_type(8)));
typedef float f32x16 __attribute__((ext_vector_type(16)));

// Gold-matching binning (R7-verified): multiply by f32-rounded reciprocal
// (RN_f32(1/0.16f) == 6.25f). DO NOT change to division.
__device__ inline void bin_xy(float px, float py, int& ix, int& iy) {
  ix = (int)floorf(px * 6.25f);
  iy = (int)floorf((py + 39.68f) * 6.25f);
  ix = min(max(ix, 0), W - 1);
  iy = min(max(iy, 0), H - 1);
}

// ---------------- Voxelization pass 1 ----------------
__global__ __launch_bounds__(256)
void count_kernel(const float* __restrict__ pts, int* __restrict__ cnt,
                  float* __restrict__ sums) {
  int p = blockIdx.x * blockDim.x + threadIdx.x;
  if (p >= Bn * Np) return;
  float px = pts[p * 4 + 0], py = pts[p * 4 + 1], pz = pts[p * 4 + 2];
  int b = p / Np;
  int ix, iy;
  bin_xy(px, py, ix, iy);
  int gid = b * HW + iy * W + ix;
  atomicAdd(&cnt[gid], 1);
  atomicAdd(&sums[3 * gid + 0], px);
  atomicAdd(&sums[3 * gid + 1], py);
  atomicAdd(&sums[3 * gid + 2], pz);
}

// ---------------- Voxelization pass 2: VFE + atomicMax scatter ----------------
// NHWC fp32 canvas in ws — lane o -> consecutive float: a wave's 64 atomics
// hit 4 cache lines instead of 64 (R8-verified win).
__global__ __launch_bounds__(256)
void vfe_kernel(const float* __restrict__ pts, const int* __restrict__ cnt,
                const float* __restrict__ sums, const float* __restrict__ vw,
                const float* __restrict__ vs, const float* __restrict__ vt,
                float* __restrict__ canv) {
  int tid = blockIdx.x * blockDim.x + threadIdx.x;
  if (tid >= Bn * Np * 64) return;
  int o = tid & 63;
  int p = tid >> 6;
  int b = p / Np;
  float px = pts[p * 4 + 0], py = pts[p * 4 + 1];
  float pz = pts[p * 4 + 2], pr = pts[p * 4 + 3];
  int ix, iy;
  bin_xy(px, py, ix, iy);
  int gid = b * HW + iy * W + ix;
  int n = cnt[gid];
  float denom = (float)max(n, 1);
  float mx = sums[3 * gid + 0] / denom;
  float my = sums[3 * gid + 1] / denom;
  float mz = sums[3 * gid + 2] / denom;
  float cx = (float)ix * 0.16f + 0.08f;
  float cy = (float)iy * 0.16f + (0.08f - 39.68f);
  float f[10] = {px, py, pz, pr, px - mx, py - my, pz - mz,
                 px - cx, py - cy, pz + 1.0f};
  const float* wr = vw + o * 10;
  float d = 0.f;
#pragma unroll
  for (int c = 0; c < 10; c++) d += f[c] * wr[c];
  float val = d * vs[o] + vt[o];
  val = fmaxf(val, 0.f);
  if (n < 32) val = fmaxf(val, fmaxf(vt[o], 0.f));
  unsigned int* dst = (unsigned int*)(canv + (size_t)gid * 64 + o);
  atomicMax(dst, __float_as_uint(val));
}

// ---------------- block1 layer0: 64->4 conv, LDS halo + scalar weights -------
// R12: R11 was latency-bound at 1.5 waves/SIMD (VALUBusy 26%, occ 14%): 128-thr
// blocks x 46KB LDS -> only 6 waves/CU. Now 256 thr = 4 waves/block: wave w
// owns (co-pair w>>1, pixel-half w&1); weight addresses stay WAVE-UNIFORM
// (scalar pipe, float2 co-pairs). 3 blocks/CU x 4 waves = 3 waves/SIMD (2x).
// Halo swizzle slot=(c4+hp)&15 unchanged (conflict floor). Per-accumulator FMA
// order (tap-major, ci-ascending) unchanged -> bit-identical output.
__global__ __launch_bounds__(256, 3)
void conv64_tile(const float* __restrict__ canv, const float* __restrict__ wc,
                 const float* __restrict__ s, const float* __restrict__ t,
                 float* __restrict__ out4) {
  __shared__ __align__(16) float hl[180 * 64];  // 46,080 B, slot-swizzled

  const int tid = threadIdx.x;
  const int b = blockIdx.y;
  const int ty = blockIdx.x / 27, tx = blockIdx.x - ty * 27;
  const int y0 = ty * 8, x0 = tx * 16;
  const float* cb = canv + (size_t)b * HW * 64;

  // stage halo 10x18 px x 64ch; store c4-block at slot (c4+hp)&15
  for (int q = tid; q < 180 * 16; q += 256) {
    int hp = q >> 4, c4 = q & 15;
    int hy = hp / 18, hx = hp - hy * 18;
    int gy = y0 - 1 + hy, gx = x0 - 1 + hx;
    float4 v = {0.f, 0.f, 0.f, 0.f};
    if ((unsigned)gy < (unsigned)H && (unsigned)gx < (unsigned)W)
      v = *(const float4*)(cb + (size_t)(gy * W + gx) * 64 + c4 * 4);
    *(float4*)(hl + hp * 64 + ((c4 + hp) & 15) * 4) = v;
  }
  __syncthreads();

  const int wv = tid >> 6, lane = tid & 63;
  const int cp = wv >> 1;                  // co pair (wave-uniform)
  const int p = (wv & 1) * 64 + lane;      // pixel 0..127
  const int ly = p >> 4, lx = p & 15;
  const int co = cp * 2;
  float a0 = 0.f, a1 = 0.f;

#pragma unroll 1
  for (int tp = 0; tp < 9; ++tp) {
    const int hp = (ly + tp / 3) * 18 + lx + tp % 3;
    const float* hb = hl + hp * 64;
    const float* wt_ = wc + tp * 256 + co;  // [ci][co0..3] rows, wave-uniform
#pragma unroll 4
    for (int c4 = 0; c4 < 16; ++c4) {
      float4 v = *(const float4*)(hb + ((c4 + hp) & 15) * 4);
      const float* wp = wt_ + c4 * 16;
      float2 w0 = *(const float2*)(wp + 0);
      float2 w1 = *(const float2*)(wp + 4);
      float2 w2 = *(const float2*)(wp + 8);
      float2 w3 = *(const float2*)(wp + 12);
      a0 = fmaf(v.x, w0.x, a0);
      a1 = fmaf(v.x, w0.y, a1);
      a0 = fmaf(v.y, w1.x, a0);
      a1 = fmaf(v.y, w1.y, a1);
      a0 = fmaf(v.z, w2.x, a0);
      a1 = fmaf(v.z, w2.y, a1);
      a0 = fmaf(v.w, w3.x, a0);
      a1 = fmaf(v.w, w3.y, a1);
    }
  }
  float* ob = out4 + (size_t)b * 4 * HW + (size_t)(y0 + ly) * W + x0 + lx;
  ob[(size_t)co * HW] = fmaxf(a0 * s[co] + t[co], 0.f);
  ob[(size_t)(co + 1) * HW] = fmaxf(a1 * s[co + 1] + t[co + 1], 0.f);
}

// ---------------- fp32 direct 3x3 conv (blocks 1 & 2) ----------------
template <int CI, int COT>
__global__ __launch_bounds__(256)
void conv3x3(const float* __restrict__ in, int in_bs, const float* __restrict__ w,
             const float* __restrict__ s, const float* __restrict__ t,
             float* __restrict__ out, int out_bs, int npix) {
  int pix = blockIdx.x * blockDim.x + threadIdx.x;
  if (pix >= npix) return;
  int b = pix / HW;
  int rem = pix - b * HW;
  int y = rem / W;
  int x = rem - y * W;
  int co0 = blockIdx.y * COT;
  const float* inb = in + (size_t)b * in_bs;

  int offs[9];
  bool okm[9];
#pragma unroll
  for (int ky = 0; ky < 3; ky++) {
    int yy = y + ky - 1;
    bool yok = (unsigned)yy < (unsigned)H;
#pragma unroll
    for (int kx = 0; kx < 3; kx++) {
      int xx = x + kx - 1;
      okm[ky * 3 + kx] = yok && ((unsigned)xx < (unsigned)W);
      offs[ky * 3 + kx] = yy * W + xx;
    }
  }
  float acc[COT];
#pragma unroll
  for (int i = 0; i < COT; i++) acc[i] = 0.f;
  for (int ci = 0; ci < CI; ci++) {
    const float* ip = inb + (size_t)ci * HW;
    float iv[9];
#pragma unroll
    for (int k = 0; k < 9; k++) iv[k] = okm[k] ? ip[offs[k]] : 0.f;
    const float* wp = w + ((size_t)co0 * CI + ci) * 9;
#pragma unroll
    for (int cg_ = 0; cg_ < COT; cg_++) {
      const float* wc_ = wp + (size_t)cg_ * CI * 9;
#pragma unroll
      for (int k = 0; k < 9; k++) acc[cg_] = fmaf(iv[k], wc_[k], acc[cg_]);
    }
  }
  float* ob = out + (size_t)b * out_bs + (size_t)rem;
#pragma unroll
  for (int cg_ = 0; cg_ < COT; cg_++) {
    float v = acc[cg_] * s[co0 + cg_] + t[co0 + cg_];
    ob[(size_t)(co0 + cg_) * HW] = fmaxf(v, 0.f);
  }
}

// ---------------- block2 last layer: 16->16 conv, DUAL output ---------------
// Writes x2 as NCHW fp32 (checked output, ch4..19) AND the same values as
// NHWC bf16 (block3 L0 input) — replaces the separate cvt dispatch.
__global__ __launch_bounds__(256)
void conv16_dual(const float* __restrict__ in, const float* __restrict__ w,
                 const float* __restrict__ s, const float* __restrict__ t,
                 float* __restrict__ out, __bf16* __restrict__ n16) {
  int pix = blockIdx.x * blockDim.x + threadIdx.x;
  if (pix >= Bn * HW) return;
  int b = pix / HW;
  int rem = pix - b * HW;
  int y = rem / W;
  int x = rem - y * W;
  const float* inb = in + (size_t)b * 16 * HW;

  int offs[9];
  bool okm[9];
#pragma unroll
  for (int ky = 0; ky < 3; ky++) {
    int yy = y + ky - 1;
    bool yok = (unsigned)yy < (unsigned)H;
#pragma unroll
    for (int kx = 0; kx < 3; kx++) {
      int xx = x + kx - 1;
      okm[ky * 3 + kx] = yok && ((unsigned)xx < (unsigned)W);
      offs[ky * 3 + kx] = yy * W + xx;
    }
  }
  float acc[16];
#pragma unroll
  for (int i = 0; i < 16; i++) acc[i] = 0.f;
  for (int ci = 0; ci < 16; ci++) {
    const float* ip = inb + (size_t)ci * HW;
    float iv[9];
#pragma unroll
    for (int k = 0; k < 9; k++) iv[k] = okm[k] ? ip[offs[k]] : 0.f;
    const float* wp = w + (size_t)ci * 9;
#pragma unroll
    for (int cg_ = 0; cg_ < 16; cg_++) {
      const float* wc_ = wp + (size_t)cg_ * 16 * 9;
#pragma unroll
      for (int k = 0; k < 9; k++) acc[cg_] = fmaf(iv[k], wc_[k], acc[cg_]);
    }
  }
  float* ob = out + (size_t)b * 84 * HW + (size_t)rem;
  __bf16 vv[16];
#pragma unroll
  for (int cg_ = 0; cg_ < 16; cg_++) {
    float v = fmaxf(acc[cg_] * s[cg_] + t[cg_], 0.f);
    ob[(size_t)cg_ * HW] = v;
    vv[cg_] = (__bf16)v;
  }
  __bf16* nb = n16 + (size_t)b * (84 * HW * 2) + (size_t)rem * 16;
  *(bf16x8*)nb = *(bf16x8*)vv;
  *(bf16x8*)(nb + 8) = *(bf16x8*)(vv + 8);
}

// ---------------- weight prepack: block3 MFMA + conv64 scalar table ----------
// Wt: fragment-ordered bf16 (1KB contiguous per wave B-frag load).
// wc64: conv64 fp32 table [tp][ci][co0..3] -> wave-uniform float4 rows.
__global__ __launch_bounds__(256)
void prepack(const float* __restrict__ w0, const float* __restrict__ ws,
             __bf16* __restrict__ wt, const float* __restrict__ w1,
             float* __restrict__ wc) {
  int idx = blockIdx.x * 256 + threadIdx.x;
  const int E0 = 64 * 144, EN = 64 * 576;
  if (idx < E0) {
    // layer0 CI=16: block = tp*2+nt (KC=1)
    int blk = idx >> 9, rem = idx & 511;
    int tp = blk >> 1, nt = blk & 1;
    int co = nt * 32 + (rem >> 4);
    int ci = rem & 15;  // = khalf*8 + e
    int ky = tp / 3, kx = tp - ky * 3;
    wt[idx] = (__bf16)w0[((co * 16 + ci) * 3 + ky) * 3 + kx];
  } else if (idx < E0 + 5 * EN) {
    int j = idx - E0;
    int n = j / EN, rr = j - n * EN;
    // CI=64: block = (tp*4+kc)*2+nt
    int blk = rr >> 9, rem = rr & 511;
    int tpkc = blk >> 1, nt = blk & 1;
    int tp = tpkc >> 2, kc = tpkc & 3;
    int co = nt * 32 + (rem >> 4);
    int ci = kc * 16 + (rem & 15);
    int ky = tp / 3, kx = tp - ky * 3;
    wt[idx] = (__bf16)ws[n * 36864 + ((co * 64 + ci) * 3 + ky) * 3 + kx];
  } else if (idx < E0 + 5 * EN + 2304) {
    int e = idx - E0 - 5 * EN;  // e = tp*256 + ci*4 + co
    int tp = e >> 8, r = e & 255;
    int ci = r >> 2, co = r & 3;
    wc[e] = w1[co * 576 + ci * 9 + tp];  // b1w0 OIHW (co,ci,ky,kx)
  }
}

// ---------------- MFMA implicit-GEMM 3x3 conv, NHWC bf16 in, BOTH batches ------
// R12: B-operand now comes from LDS. Previous structure read the weight
// fragments from GLOBAL (L2) inside the MFMA loop: 72 loads x ~200cy per wave
// vs 1152 MFMA cycles -> latency-bound at ~16% MFMA util (why R2/R5 pipeline/
// occupancy tweaks were neutral). Now kc-OUTER: per kc, cooperatively stage the
// 18KB weight slab (9 taps x 2 ntiles) into LDS, then 9 taps x 4 MFMA all from
// LDS (both conflict-free b128 patterns). LDS 65KB -> 2 blocks/CU (R5 showed
// 2 vs 3 blocks is neutral). kc-major reorders the same 36 fp32 MFMA
// contributions per acc -> absmax may drift ~1e-3 (threshold 4.7e-2); KC=1
// layer (CI=16) is order-identical.
// FINAL: BN+ReLU then LDS-transpose (two 128-px chunks) -> coalesced NCHW fp32.
template <int CI, bool FINAL>
__global__ __launch_bounds__(256, 2)
void mconv(const __bf16* __restrict__ in, size_t in_bstride,
           const __bf16* __restrict__ wt, const float* __restrict__ s,
           const float* __restrict__ t, __bf16* __restrict__ outb,
           size_t outb_bstride, float* __restrict__ outf, size_t outf_bstride) {
  constexpr int KC = CI / 16;
  constexpr int PADW = (CI == 64) ? 72 : 24;  // bf16 per-pixel stride; 16B-aligned
  constexpr int HALO_B = 324 * PADW * 2;      // 18x18 pixels
  constexpr int TRAN_B = FINAL ? 128 * 66 * 4 : 0;
  constexpr int HT_B = HALO_B > TRAN_B ? HALO_B : TRAN_B;  // 46656 for CI=64
  constexpr int SMEM_B = HT_B + 18432;  // + per-kc weight slab
  __shared__ __align__(16) char smem[SMEM_B];
  __bf16* hl = (__bf16*)smem;
  __bf16* wb = (__bf16*)(smem + HT_B);

  const int tid = threadIdx.x;
  const int bz = blockIdx.y;
  const int ty = blockIdx.x / 27, tx = blockIdx.x - ty * 27;
  const int y0 = ty * 16, x0 = tx * 16;
  in += (size_t)bz * in_bstride;

  // stage halo: 18x18 pixels x CI channels (zeros outside image)
  constexpr int NCH = CI / 8;
  constexpr int TOT = 324 * NCH;
  for (int q = tid; q < TOT; q += 256) {
    int hp = q / NCH, c8 = q - hp * NCH;
    int hy = hp / 18, hx = hp - hy * 18;
    int gy = y0 - 1 + hy, gx = x0 - 1 + hx;
    int4 v = {0, 0, 0, 0};
    if ((unsigned)gy < (unsigned)H && (unsigned)gx < (unsigned)W)
      v = *(const int4*)(in + (size_t)(gy * W + gx) * CI + c8 * 8);
    *(int4*)(hl + hp * PADW + c8 * 8) = v;
  }

  const int lane = tid & 63;
  const int wv = tid >> 6;
  const int col = lane & 31, half = lane >> 5;
  const int ly0 = 4 * wv + (col >> 4);  // A: m = col -> pixel row of m-tile 0
  const int lx = col & 15;

  f32x16 z = {0.f, 0.f, 0.f, 0.f, 0.f, 0.f, 0.f, 0.f,
              0.f, 0.f, 0.f, 0.f, 0.f, 0.f, 0.f, 0.f};
  f32x16 a00 = z, a01 = z, a10 = z, a11 = z;  // [mtile][ntile]

  const int laneoff = col * 16 + half * 8;

  for (int kc = 0; kc < KC; ++kc) {
    if (kc) __syncthreads();  // prev kc's wb reads complete
    // stage weight slab for this kc: 9 taps x 1024 elems (2 ntiles)
    for (int q = tid; q < 1152; q += 256) {
      int tp = q >> 7, wi = (q & 127) * 8;
      *(int4*)(wb + tp * 1024 + wi) =
          *(const int4*)(wt + ((tp * KC + kc) << 10) + wi);
    }
    __syncthreads();  // halo (kc==0) + weight slab ready
#pragma unroll
    for (int tp = 0; tp < 9; ++tp) {
      const __bf16* a0r =
          hl + ((ly0 + tp / 3) * 18 + lx + tp % 3) * PADW + half * 8 + kc * 16;
      const __bf16* a1r = a0r + 2 * 18 * PADW;  // m-tile 1: +2 pixel rows
      const __bf16* bb = wb + tp * 1024 + laneoff;
      bf16x8 af0 = *(const bf16x8*)a0r;
      bf16x8 af1 = *(const bf16x8*)a1r;
      bf16x8 b0 = *(const bf16x8*)bb;
      bf16x8 b1 = *(const bf16x8*)(bb + 512);
      a00 = __builtin_amdgcn_mfma_f32_32x32x16_bf16(af0, b0, a00, 0, 0, 0);
      a01 = __builtin_amdgcn_mfma_f32_32x32x16_bf16(af0, b1, a01, 0, 0, 0);
      a10 = __builtin_amdgcn_mfma_f32_32x32x16_bf16(af1, b0, a10, 0, 0, 0);
      a11 = __builtin_amdgcn_mfma_f32_32x32x16_bf16(af1, b1, a11, 0, 0, 0);
    }
  }

  float s0 = s[col], t0v = t[col], s1 = s[col + 32], t1v = t[col + 32];
  if constexpr (!FINAL) {
    __bf16* ob = outb + (size_t)bz * outb_bstride;
#pragma unroll
    for (int r = 0; r < 16; ++r) {
      int row = (r & 3) + 8 * (r >> 2) + 4 * half;  // verified C/D map (m74/m101)
      int py = y0 + 4 * wv + (row >> 4);
      int px = x0 + (row & 15);
      size_t gp0 = (size_t)py * W + px;
      size_t gp1 = gp0 + (size_t)2 * W;  // m-tile 1
      ob[gp0 * 64 + col] = (__bf16)fmaxf(a00[r] * s0 + t0v, 0.f);
      ob[gp0 * 64 + col + 32] = (__bf16)fmaxf(a01[r] * s1 + t1v, 0.f);
      ob[gp1 * 64 + col] = (__bf16)fmaxf(a10[r] * s0 + t0v, 0.f);
      ob[gp1 * 64 + col + 32] = (__bf16)fmaxf(a11[r] * s1 + t1v, 0.f);
    }
  } else {
    float* of = outf + (size_t)bz * outf_bstride;
    float* tl = (float*)smem;
    // two 128-pixel chunks (waves {0,1} then {2,3}) so tl fits under halo size
    for (int h = 0; h < 2; ++h) {
      __syncthreads();  // h=0: halo/wb reads done; h=1: chunk-0 stores done
      if ((wv >> 1) == h) {
        int wl_ = wv & 1;
#pragma unroll
        for (int r = 0; r < 16; ++r) {
          int row = (r & 3) + 8 * (r >> 2) + 4 * half;
          int lp0 = (4 * wl_ + (row >> 4)) * 16 + (row & 15);
          int lp1 = lp0 + 32;  // +2 pixel rows
          tl[lp0 * 66 + col] = fmaxf(a00[r] * s0 + t0v, 0.f);
          tl[lp0 * 66 + col + 32] = fmaxf(a01[r] * s1 + t1v, 0.f);
          tl[lp1 * 66 + col] = fmaxf(a10[r] * s0 + t0v, 0.f);
          tl[lp1 * 66 + col + 32] = fmaxf(a11[r] * s1 + t1v, 0.f);
        }
      }
      __syncthreads();
      for (int e = tid; e < 128 * 64; e += 256) {
        int co = e >> 7, mtl = e & 127;
        of[(size_t)co * HW + (size_t)(y0 + h * 8 + (mtl >> 4)) * W +
           (x0 + (mtl & 15))] = tl[mtl * 66 + co];
      }
    }
  }
}

extern "C" void kernel_launch(void* const* d_in, const int* in_sizes, int n_in,
                              void* d_out, int out_size, void* d_ws, size_t ws_size,
                              hipStream_t stream) {
  const float* pts  = (const float*)d_in[0];
  const float* vw   = (const float*)d_in[1];
  const float* vs   = (const float*)d_in[2];
  const float* vt   = (const float*)d_in[3];
  const float* b1w0 = (const float*)d_in[4];
  const float* b1s0 = (const float*)d_in[5];
  const float* b1t0 = (const float*)d_in[6];
  const float* b1w  = (const float*)d_in[7];
  const float* b1s  = (const float*)d_in[8];
  const float* b1t  = (const float*)d_in[9];
  const float* b2w0 = (const float*)d_in[10];
  const float* b2s0 = (const float*)d_in[11];
  const float* b2t0 = (const float*)d_in[12];
  const float* b2w  = (const float*)d_in[13];
  const float* b2s  = (const float*)d_in[14];
  const float* b2t  = (const float*)d_in[15];
  const float* b3w0 = (const float*)d_in[16];
  const float* b3s0 = (const float*)d_in[17];
  const float* b3t0 = (const float*)d_in[18];
  const float* b3w  = (const float*)d_in[19];
  const float* b3s  = (const float*)d_in[20];
  const float* b3t  = (const float*)d_in[21];
  float* out = (float*)d_out;

  // ws layout (peak ~165MB):
  //  [0, 8HW) floats:      vox cnt (2HW ints) + sums (6HW floats)
  //  [0, 64HW) floats:     s16a / s16b (block1/2 ping-pong); later ppA bf16
  //  [64HW, 192HW) floats: NHWC fp32 canvas (vfe scatter; dead after conv64)
  //  [192HW*4, +387KB):    Wt bf16 (prepacked up front, disjoint from all)
  //  [192HW*4 + 512KB, +9216B): wc64 fp32 conv64 weight table
  float* wsf = (float*)d_ws;
  int* cnt = (int*)wsf;
  float* sums = wsf + (size_t)2 * HW;
  float* s16a = wsf;
  float* s16b = wsf + (size_t)32 * HW;
  float* canv = wsf + (size_t)64 * HW;               // 128HW floats
  __bf16* ppA = (__bf16*)d_ws;                       // + b*64*HW elements
  __bf16* Wt = (__bf16*)((char*)d_ws + (size_t)192 * HW * 4);
  float* wc64 = (float*)((char*)d_ws + (size_t)192 * HW * 4 + 512 * 1024);

  // prepack first: no deps, off the critical path
  prepack<<<765, 256, 0, stream>>>(b3w0, b3w, Wt, b1w0, wc64);

  hipMemsetAsync(cnt, 0, (size_t)8 * HW * sizeof(float), stream);
  hipMemsetAsync(canv, 0, (size_t)128 * HW * sizeof(float), stream);

  count_kernel<<<(Bn * Np + 255) / 256, 256, 0, stream>>>(pts, cnt, sums);
  vfe_kernel<<<(Bn * Np * 64 + 255) / 256, 256, 0, stream>>>(pts, cnt, sums, vw, vs,
                                                             vt, canv);

  const int g2 = (2 * HW + 255) / 256;
  dim3 blk(256);

  // block1: 64->4 (NHWC canvas, LDS halo + scalar weights), 3x(4->4)
  conv64_tile<<<dim3(27 * 62, Bn), blk, 0, stream>>>(canv, wc64, b1s0, b1t0, s16a);
  conv3x3<4, 4><<<dim3(g2, 1), blk, 0, stream>>>(s16a, 4 * HW, b1w + 0 * 144,
                                                 b1s + 0, b1t + 0, s16b, 4 * HW,
                                                 2 * HW);
  conv3x3<4, 4><<<dim3(g2, 1), blk, 0, stream>>>(s16b, 4 * HW, b1w + 1 * 144,
                                                 b1s + 4, b1t + 4, s16a, 4 * HW,
                                                 2 * HW);
  conv3x3<4, 4><<<dim3(g2, 1), blk, 0, stream>>>(s16a, 4 * HW, b1w + 2 * 144,
                                                 b1s + 8, b1t + 8, out, 84 * HW,
                                                 2 * HW);

  // block2: 4->16, 4x(16->16), then DUAL last layer; x2 -> out ch4..19 + n16
  __bf16* n16 = (__bf16*)(out + (size_t)20 * HW);  // out ch20..83 reuse (dead)
  conv3x3<4, 16><<<dim3(g2, 1), blk, 0, stream>>>(out, 84 * HW, b2w0, b2s0, b2t0,
                                                  s16a, 16 * HW, 2 * HW);
  conv3x3<16, 16><<<dim3(g2, 1), blk, 0, stream>>>(s16a, 16 * HW, b2w + 0 * 2304,
                                                   b2s + 0, b2t + 0, s16b, 16 * HW,
                                                   2 * HW);
  conv3x3<16, 16><<<dim3(g2, 1), blk, 0, stream>>>(s16b, 16 * HW, b2w + 1 * 2304,
                                                   b2s + 16, b2t + 16, s16a, 16 * HW,
                                                   2 * HW);
  conv3x3<16, 16><<<dim3(g2, 1), blk, 0, stream>>>(s16a, 16 * HW, b2w + 2 * 2304,
                                                   b2s + 32, b2t + 32, s16b, 16 * HW,
                                                   2 * HW);
  conv3x3<16, 16><<<dim3(g2, 1), blk, 0, stream>>>(s16b, 16 * HW, b2w + 3 * 2304,
                                                   b2s + 48, b2t + 48, s16a, 16 * HW,
                                                   2 * HW);
  conv16_dual<<<g2, blk, 0, stream>>>(s16a, b2w + 4 * 2304, b2s + 64, b2t + 64,
                                      out + 4 * HW, n16);

  // block3 via MFMA, BOTH batches per dispatch (grid.y = Bn).
  const size_t canv_s = (size_t)84 * HW * 2;  // bf16 elems per batch
  const size_t ppa_s = (size_t)64 * HW;
  dim3 mg(31 * 27, Bn);  // 16x16-pixel tiles x batches
  mconv<16, false><<<mg, blk, 0, stream>>>(n16, canv_s, Wt, b3s0, b3t0, ppA, ppa_s,
                                           nullptr, 0);
  mconv<64, false><<<mg, blk, 0, stream>>>(ppA, ppa_s, Wt + 9216 + 0 * 36864,
                                           b3s + 0, b3t + 0, n16, canv_s, nullptr,
                                           0);
  mconv<64, false><<<mg, blk, 0, stream>>>(n16, canv_s, Wt + 9216 + 1 * 36864,
                                           b3s + 64, b3t + 64, ppA, ppa_s, nullptr,
                                           0);
  mconv<64, false><<<mg, blk, 0, stream>>>(ppA, ppa_s, Wt + 9216 + 2 * 36864,
                                           b3s + 128, b3t + 128, n16, canv_s,
                                           nullptr, 0);
  mconv<64, false><<<mg, blk, 0, stream>>>(n16, canv_s, Wt + 9216 + 3 * 36864,
                                           b3s + 192, b3t + 192, ppA, ppa_s,
                                           nullptr, 0);
  mconv<64, true><<<mg, blk, 0, stream>>>(ppA, ppa_s, Wt + 9216 + 4 * 36864,
                                          b3s + 256, b3t + 256, nullptr, 0,
                                          out + (size_t)20 * HW, (size_t)84 * HW);
}

// Round 13
// 823.509 us; speedup vs baseline: 1.2354x; 1.2354x over previous
//
#include <hip/hip_runtime.h>
#include <math.h>

static constexpr int H = 496, W = 432, Bn = 2, Np = 16000;
static constexpr int HW = H * W;  // 214272

typedef __bf16 bf16x8 __attribute__((ext_vector_type(8)));
typedef float f32x16 __attribute__((ext_vector_type(16)));

// Gold-matching binning (R7-verified): multiply by f32-rounded reciprocal
// (RN_f32(1/0.16f) == 6.25f). DO NOT change to division.
__device__ inline void bin_xy(float px, float py, int& ix, int& iy) {
  ix = (int)floorf(px * 6.25f);
  iy = (int)floorf((py + 39.68f) * 6.25f);
  ix = min(max(ix, 0), W - 1);
  iy = min(max(iy, 0), H - 1);
}

// ---------------- Voxelization pass 1 ----------------
__global__ __launch_bounds__(256)
void count_kernel(const float* __restrict__ pts, int* __restrict__ cnt,
                  float* __restrict__ sums) {
  int p = blockIdx.x * blockDim.x + threadIdx.x;
  if (p >= Bn * Np) return;
  float px = pts[p * 4 + 0], py = pts[p * 4 + 1], pz = pts[p * 4 + 2];
  int b = p / Np;
  int ix, iy;
  bin_xy(px, py, ix, iy);
  int gid = b * HW + iy * W + ix;
  atomicAdd(&cnt[gid], 1);
  atomicAdd(&sums[3 * gid + 0], px);
  atomicAdd(&sums[3 * gid + 1], py);
  atomicAdd(&sums[3 * gid + 2], pz);
}

// ---------------- Voxelization pass 2: VFE + atomicMax scatter ----------------
// NHWC fp32 canvas in ws — lane o -> consecutive float: a wave's 64 atomics
// hit 4 cache lines instead of 64 (R8-verified win).
__global__ __launch_bounds__(256)
void vfe_kernel(const float* __restrict__ pts, const int* __restrict__ cnt,
                const float* __restrict__ sums, const float* __restrict__ vw,
                const float* __restrict__ vs, const float* __restrict__ vt,
                float* __restrict__ canv) {
  int tid = blockIdx.x * blockDim.x + threadIdx.x;
  if (tid >= Bn * Np * 64) return;
  int o = tid & 63;
  int p = tid >> 6;
  int b = p / Np;
  float px = pts[p * 4 + 0], py = pts[p * 4 + 1];
  float pz = pts[p * 4 + 2], pr = pts[p * 4 + 3];
  int ix, iy;
  bin_xy(px, py, ix, iy);
  int gid = b * HW + iy * W + ix;
  int n = cnt[gid];
  float denom = (float)max(n, 1);
  float mx = sums[3 * gid + 0] / denom;
  float my = sums[3 * gid + 1] / denom;
  float mz = sums[3 * gid + 2] / denom;
  float cx = (float)ix * 0.16f + 0.08f;
  float cy = (float)iy * 0.16f + (0.08f - 39.68f);
  float f[10] = {px, py, pz, pr, px - mx, py - my, pz - mz,
                 px - cx, py - cy, pz + 1.0f};
  const float* wr = vw + o * 10;
  float d = 0.f;
#pragma unroll
  for (int c = 0; c < 10; c++) d += f[c] * wr[c];
  float val = d * vs[o] + vt[o];
  val = fmaxf(val, 0.f);
  if (n < 32) val = fmaxf(val, fmaxf(vt[o], 0.f));
  unsigned int* dst = (unsigned int*)(canv + (size_t)gid * 64 + o);
  atomicMax(dst, __float_as_uint(val));
}

// ---------------- block1 layer0: 64->4 conv, LDS halo + scalar weights -------
// R11-verified (98us): 1 thread/pixel computes ALL 4 co, weights from a
// prepacked [tp][ci][co0..3] table at a WAVE-UNIFORM address -> s_load on the
// scalar pipe (no LDS/VALU issue cost). Halo PADP=64 with slot swizzle
// slot=(c4+hp)&15 (4-way residual conflict = b128 floor). R12's 4-wave co-split
// REGRESSED (243us: halo reads duplicated per co-pair wave, conflicts 2x) —
// do not reintroduce. FMA order tap-major, ci-ascending -> bit-identical.
__global__ __launch_bounds__(128, 2)
void conv64_tile(const float* __restrict__ canv, const float* __restrict__ wc,
                 const float* __restrict__ s, const float* __restrict__ t,
                 float* __restrict__ out4) {
  __shared__ __align__(16) float hl[180 * 64];  // 46,080 B, slot-swizzled

  const int tid = threadIdx.x;  // = pixel within 8x16 tile
  const int b = blockIdx.y;
  const int ty = blockIdx.x / 27, tx = blockIdx.x - ty * 27;
  const int y0 = ty * 8, x0 = tx * 16;
  const float* cb = canv + (size_t)b * HW * 64;

  // stage halo 10x18 px x 64ch; store c4-block at slot (c4+hp)&15
  for (int q = tid; q < 180 * 16; q += 128) {
    int hp = q >> 4, c4 = q & 15;
    int hy = hp / 18, hx = hp - hy * 18;
    int gy = y0 - 1 + hy, gx = x0 - 1 + hx;
    float4 v = {0.f, 0.f, 0.f, 0.f};
    if ((unsigned)gy < (unsigned)H && (unsigned)gx < (unsigned)W)
      v = *(const float4*)(cb + (size_t)(gy * W + gx) * 64 + c4 * 4);
    *(float4*)(hl + hp * 64 + ((c4 + hp) & 15) * 4) = v;
  }
  __syncthreads();

  const int ly = tid >> 4, lx = tid & 15;
  float a0 = 0.f, a1 = 0.f, a2 = 0.f, a3 = 0.f;

#pragma unroll 1
  for (int tp = 0; tp < 9; ++tp) {
    const int hp = (ly + tp / 3) * 18 + lx + tp % 3;
    const float* hb = hl + hp * 64;
    const float* wt_ = wc + tp * 256;  // [ci][co0..3], wave-uniform
#pragma unroll 4
    for (int c4 = 0; c4 < 16; ++c4) {
      float4 v = *(const float4*)(hb + ((c4 + hp) & 15) * 4);
      float4 wq0 = *(const float4*)(wt_ + (c4 * 4 + 0) * 4);
      float4 wq1 = *(const float4*)(wt_ + (c4 * 4 + 1) * 4);
      float4 wq2 = *(const float4*)(wt_ + (c4 * 4 + 2) * 4);
      float4 wq3 = *(const float4*)(wt_ + (c4 * 4 + 3) * 4);
      a0 = fmaf(v.x, wq0.x, a0);
      a1 = fmaf(v.x, wq0.y, a1);
      a2 = fmaf(v.x, wq0.z, a2);
      a3 = fmaf(v.x, wq0.w, a3);
      a0 = fmaf(v.y, wq1.x, a0);
      a1 = fmaf(v.y, wq1.y, a1);
      a2 = fmaf(v.y, wq1.z, a2);
      a3 = fmaf(v.y, wq1.w, a3);
      a0 = fmaf(v.z, wq2.x, a0);
      a1 = fmaf(v.z, wq2.y, a1);
      a2 = fmaf(v.z, wq2.z, a2);
      a3 = fmaf(v.z, wq2.w, a3);
      a0 = fmaf(v.w, wq3.x, a0);
      a1 = fmaf(v.w, wq3.y, a1);
      a2 = fmaf(v.w, wq3.z, a2);
      a3 = fmaf(v.w, wq3.w, a3);
    }
  }
  float* ob = out4 + (size_t)b * 4 * HW + (size_t)(y0 + ly) * W + x0 + lx;
  ob[0 * HW] = fmaxf(a0 * s[0] + t[0], 0.f);
  ob[1 * HW] = fmaxf(a1 * s[1] + t[1], 0.f);
  ob[2 * HW] = fmaxf(a2 * s[2] + t[2], 0.f);
  ob[3 * HW] = fmaxf(a3 * s[3] + t[3], 0.f);
}

// ---------------- fp32 direct 3x3 conv (blocks 1 & 2) ----------------
template <int CI, int COT>
__global__ __launch_bounds__(256)
void conv3x3(const float* __restrict__ in, int in_bs, const float* __restrict__ w,
             const float* __restrict__ s, const float* __restrict__ t,
             float* __restrict__ out, int out_bs, int npix) {
  int pix = blockIdx.x * blockDim.x + threadIdx.x;
  if (pix >= npix) return;
  int b = pix / HW;
  int rem = pix - b * HW;
  int y = rem / W;
  int x = rem - y * W;
  int co0 = blockIdx.y * COT;
  const float* inb = in + (size_t)b * in_bs;

  int offs[9];
  bool okm[9];
#pragma unroll
  for (int ky = 0; ky < 3; ky++) {
    int yy = y + ky - 1;
    bool yok = (unsigned)yy < (unsigned)H;
#pragma unroll
    for (int kx = 0; kx < 3; kx++) {
      int xx = x + kx - 1;
      okm[ky * 3 + kx] = yok && ((unsigned)xx < (unsigned)W);
      offs[ky * 3 + kx] = yy * W + xx;
    }
  }
  float acc[COT];
#pragma unroll
  for (int i = 0; i < COT; i++) acc[i] = 0.f;
  for (int ci = 0; ci < CI; ci++) {
    const float* ip = inb + (size_t)ci * HW;
    float iv[9];
#pragma unroll
    for (int k = 0; k < 9; k++) iv[k] = okm[k] ? ip[offs[k]] : 0.f;
    const float* wp = w + ((size_t)co0 * CI + ci) * 9;
#pragma unroll
    for (int cg_ = 0; cg_ < COT; cg_++) {
      const float* wc_ = wp + (size_t)cg_ * CI * 9;
#pragma unroll
      for (int k = 0; k < 9; k++) acc[cg_] = fmaf(iv[k], wc_[k], acc[cg_]);
    }
  }
  float* ob = out + (size_t)b * out_bs + (size_t)rem;
#pragma unroll
  for (int cg_ = 0; cg_ < COT; cg_++) {
    float v = acc[cg_] * s[co0 + cg_] + t[co0 + cg_];
    ob[(size_t)(co0 + cg_) * HW] = fmaxf(v, 0.f);
  }
}

// ---------------- block2 last layer: 16->16 conv, DUAL output ---------------
// Writes x2 as NCHW fp32 (checked output, ch4..19) AND the same values as
// NHWC bf16 (block3 L0 input) — replaces the separate cvt dispatch.
__global__ __launch_bounds__(256)
void conv16_dual(const float* __restrict__ in, const float* __restrict__ w,
                 const float* __restrict__ s, const float* __restrict__ t,
                 float* __restrict__ out, __bf16* __restrict__ n16) {
  int pix = blockIdx.x * blockDim.x + threadIdx.x;
  if (pix >= Bn * HW) return;
  int b = pix / HW;
  int rem = pix - b * HW;
  int y = rem / W;
  int x = rem - y * W;
  const float* inb = in + (size_t)b * 16 * HW;

  int offs[9];
  bool okm[9];
#pragma unroll
  for (int ky = 0; ky < 3; ky++) {
    int yy = y + ky - 1;
    bool yok = (unsigned)yy < (unsigned)H;
#pragma unroll
    for (int kx = 0; kx < 3; kx++) {
      int xx = x + kx - 1;
      okm[ky * 3 + kx] = yok && ((unsigned)xx < (unsigned)W);
      offs[ky * 3 + kx] = yy * W + xx;
    }
  }
  float acc[16];
#pragma unroll
  for (int i = 0; i < 16; i++) acc[i] = 0.f;
  for (int ci = 0; ci < 16; ci++) {
    const float* ip = inb + (size_t)ci * HW;
    float iv[9];
#pragma unroll
    for (int k = 0; k < 9; k++) iv[k] = okm[k] ? ip[offs[k]] : 0.f;
    const float* wp = w + (size_t)ci * 9;
#pragma unroll
    for (int cg_ = 0; cg_ < 16; cg_++) {
      const float* wc_ = wp + (size_t)cg_ * 16 * 9;
#pragma unroll
      for (int k = 0; k < 9; k++) acc[cg_] = fmaf(iv[k], wc_[k], acc[cg_]);
    }
  }
  float* ob = out + (size_t)b * 84 * HW + (size_t)rem;
  __bf16 vv[16];
#pragma unroll
  for (int cg_ = 0; cg_ < 16; cg_++) {
    float v = fmaxf(acc[cg_] * s[cg_] + t[cg_], 0.f);
    ob[(size_t)cg_ * HW] = v;
    vv[cg_] = (__bf16)v;
  }
  __bf16* nb = n16 + (size_t)b * (84 * HW * 2) + (size_t)rem * 16;
  *(bf16x8*)nb = *(bf16x8*)vv;
  *(bf16x8*)(nb + 8) = *(bf16x8*)(vv + 8);
}

// ---------------- weight prepack: block3 MFMA + conv64 scalar table ----------
// Wt: fragment-ordered bf16 (1KB contiguous per wave B-frag load).
// wc64: conv64 fp32 table [tp][ci][co0..3] -> wave-uniform float4 rows.
__global__ __launch_bounds__(256)
void prepack(const float* __restrict__ w0, const float* __restrict__ ws,
             __bf16* __restrict__ wt, const float* __restrict__ w1,
             float* __restrict__ wc) {
  int idx = blockIdx.x * 256 + threadIdx.x;
  const int E0 = 64 * 144, EN = 64 * 576;
  if (idx < E0) {
    // layer0 CI=16: block = tp*2+nt (KC=1)
    int blk = idx >> 9, rem = idx & 511;
    int tp = blk >> 1, nt = blk & 1;
    int co = nt * 32 + (rem >> 4);
    int ci = rem & 15;  // = khalf*8 + e
    int ky = tp / 3, kx = tp - ky * 3;
    wt[idx] = (__bf16)w0[((co * 16 + ci) * 3 + ky) * 3 + kx];
  } else if (idx < E0 + 5 * EN) {
    int j = idx - E0;
    int n = j / EN, rr = j - n * EN;
    // CI=64: block = (tp*4+kc)*2+nt
    int blk = rr >> 9, rem = rr & 511;
    int tpkc = blk >> 1, nt = blk & 1;
    int tp = tpkc >> 2, kc = tpkc & 3;
    int co = nt * 32 + (rem >> 4);
    int ci = kc * 16 + (rem & 15);
    int ky = tp / 3, kx = tp - ky * 3;
    wt[idx] = (__bf16)ws[n * 36864 + ((co * 64 + ci) * 3 + ky) * 3 + kx];
  } else if (idx < E0 + 5 * EN + 2304) {
    int e = idx - E0 - 5 * EN;  // e = tp*256 + ci*4 + co
    int tp = e >> 8, r = e & 255;
    int ci = r >> 2, co = r & 3;
    wc[e] = w1[co * 576 + ci * 9 + tp];  // b1w0 OIHW (co,ci,ky,kx)
  }
}

// ---------------- MFMA implicit-GEMM 3x3 conv, NHWC bf16 in, BOTH batches ------
// R5/R11-verified kernel (do not restructure: R2 pipeline, R5 occupancy, R12
// kc-outer LDS-weights all neutral-to-negative). wg = 256 thr (4 waves), tile
// 16x16 px x 64 co. Halo (18x18 x CI) staged once in LDS. Wave wv owns 64 px
// as 2 m-tiles x 2 n-tiles (4 f32x16 accs). grid = (837, Bn).
// FINAL: BN+ReLU then LDS-transpose (two 128-px chunks) -> coalesced NCHW fp32.
template <int CI, bool FINAL>
__global__ __launch_bounds__(256, 3)
void mconv(const __bf16* __restrict__ in, size_t in_bstride,
           const __bf16* __restrict__ wt, const float* __restrict__ s,
           const float* __restrict__ t, __bf16* __restrict__ outb,
           size_t outb_bstride, float* __restrict__ outf, size_t outf_bstride) {
  constexpr int KC = CI / 16;
  constexpr int PADW = (CI == 64) ? 72 : 24;  // bf16 per-pixel stride; 16B-aligned
  constexpr int HALO_B = 324 * PADW * 2;      // 18x18 pixels
  constexpr int TRAN_B = FINAL ? 128 * 66 * 4 : 0;
  constexpr int SMEM_B = HALO_B > TRAN_B ? HALO_B : TRAN_B;  // 46656 for CI=64
  __shared__ __align__(16) char smem[SMEM_B];
  __bf16* hl = (__bf16*)smem;

  const int tid = threadIdx.x;
  const int bz = blockIdx.y;
  const int ty = blockIdx.x / 27, tx = blockIdx.x - ty * 27;
  const int y0 = ty * 16, x0 = tx * 16;
  in += (size_t)bz * in_bstride;

  // stage halo: 18x18 pixels x CI channels (zeros outside image)
  constexpr int NCH = CI / 8;
  constexpr int TOT = 324 * NCH;
  for (int q = tid; q < TOT; q += 256) {
    int hp = q / NCH, c8 = q - hp * NCH;
    int hy = hp / 18, hx = hp - hy * 18;
    int gy = y0 - 1 + hy, gx = x0 - 1 + hx;
    int4 v = {0, 0, 0, 0};
    if ((unsigned)gy < (unsigned)H && (unsigned)gx < (unsigned)W)
      v = *(const int4*)(in + (size_t)(gy * W + gx) * CI + c8 * 8);
    *(int4*)(hl + hp * PADW + c8 * 8) = v;
  }
  __syncthreads();

  const int lane = tid & 63;
  const int wv = tid >> 6;
  const int col = lane & 31, half = lane >> 5;
  const int ly0 = 4 * wv + (col >> 4);  // A: m = col -> pixel row of m-tile 0
  const int lx = col & 15;

  f32x16 z = {0.f, 0.f, 0.f, 0.f, 0.f, 0.f, 0.f, 0.f,
              0.f, 0.f, 0.f, 0.f, 0.f, 0.f, 0.f, 0.f};
  f32x16 a00 = z, a01 = z, a10 = z, a11 = z;  // [mtile][ntile]

  const int laneoff = col * 16 + half * 8;
  const __bf16* wbase = wt + laneoff;

#pragma unroll
  for (int tp = 0; tp < 9; ++tp) {
    const __bf16* a0r = hl + ((ly0 + tp / 3) * 18 + lx + tp % 3) * PADW + half * 8;
    const __bf16* a1r = a0r + 2 * 18 * PADW;  // m-tile 1: +2 pixel rows
    const __bf16* bb = wbase + ((tp * KC) << 10);
#pragma unroll
    for (int kc = 0; kc < KC; ++kc) {
      bf16x8 af0 = *(const bf16x8*)(a0r + kc * 16);
      bf16x8 af1 = *(const bf16x8*)(a1r + kc * 16);
      bf16x8 b0 = *(const bf16x8*)(bb + (kc << 10));
      bf16x8 b1 = *(const bf16x8*)(bb + (kc << 10) + 512);
      a00 = __builtin_amdgcn_mfma_f32_32x32x16_bf16(af0, b0, a00, 0, 0, 0);
      a01 = __builtin_amdgcn_mfma_f32_32x32x16_bf16(af0, b1, a01, 0, 0, 0);
      a10 = __builtin_amdgcn_mfma_f32_32x32x16_bf16(af1, b0, a10, 0, 0, 0);
      a11 = __builtin_amdgcn_mfma_f32_32x32x16_bf16(af1, b1, a11, 0, 0, 0);
    }
  }

  float s0 = s[col], t0v = t[col], s1 = s[col + 32], t1v = t[col + 32];
  if constexpr (!FINAL) {
    __bf16* ob = outb + (size_t)bz * outb_bstride;
#pragma unroll
    for (int r = 0; r < 16; ++r) {
      int row = (r & 3) + 8 * (r >> 2) + 4 * half;  // verified C/D map (m74/m101)
      int py = y0 + 4 * wv + (row >> 4);
      int px = x0 + (row & 15);
      size_t gp0 = (size_t)py * W + px;
      size_t gp1 = gp0 + (size_t)2 * W;  // m-tile 1
      ob[gp0 * 64 + col] = (__bf16)fmaxf(a00[r] * s0 + t0v, 0.f);
      ob[gp0 * 64 + col + 32] = (__bf16)fmaxf(a01[r] * s1 + t1v, 0.f);
      ob[gp1 * 64 + col] = (__bf16)fmaxf(a10[r] * s0 + t0v, 0.f);
      ob[gp1 * 64 + col + 32] = (__bf16)fmaxf(a11[r] * s1 + t1v, 0.f);
    }
  } else {
    float* of = outf + (size_t)bz * outf_bstride;
    float* tl = (float*)smem;
    // two 128-pixel chunks (waves {0,1} then {2,3}) so tl fits under halo size
    for (int h = 0; h < 2; ++h) {
      __syncthreads();  // h=0: halo reads done; h=1: chunk-0 stores done
      if ((wv >> 1) == h) {
        int wl_ = wv & 1;
#pragma unroll
        for (int r = 0; r < 16; ++r) {
          int row = (r & 3) + 8 * (r >> 2) + 4 * half;
          int lp0 = (4 * wl_ + (row >> 4)) * 16 + (row & 15);
          int lp1 = lp0 + 32;  // +2 pixel rows
          tl[lp0 * 66 + col] = fmaxf(a00[r] * s0 + t0v, 0.f);
          tl[lp0 * 66 + col + 32] = fmaxf(a01[r] * s1 + t1v, 0.f);
          tl[lp1 * 66 + col] = fmaxf(a10[r] * s0 + t0v, 0.f);
          tl[lp1 * 66 + col + 32] = fmaxf(a11[r] * s1 + t1v, 0.f);
        }
      }
      __syncthreads();
      for (int e = tid; e < 128 * 64; e += 256) {
        int co = e >> 7, mtl = e & 127;
        of[(size_t)co * HW + (size_t)(y0 + h * 8 + (mtl >> 4)) * W +
           (x0 + (mtl & 15))] = tl[mtl * 66 + co];
      }
    }
  }
}

extern "C" void kernel_launch(void* const* d_in, const int* in_sizes, int n_in,
                              void* d_out, int out_size, void* d_ws, size_t ws_size,
                              hipStream_t stream) {
  const float* pts  = (const float*)d_in[0];
  const float* vw   = (const float*)d_in[1];
  const float* vs   = (const float*)d_in[2];
  const float* vt   = (const float*)d_in[3];
  const float* b1w0 = (const float*)d_in[4];
  const float* b1s0 = (const float*)d_in[5];
  const float* b1t0 = (const float*)d_in[6];
  const float* b1w  = (const float*)d_in[7];
  const float* b1s  = (const float*)d_in[8];
  const float* b1t  = (const float*)d_in[9];
  const float* b2w0 = (const float*)d_in[10];
  const float* b2s0 = (const float*)d_in[11];
  const float* b2t0 = (const float*)d_in[12];
  const float* b2w  = (const float*)d_in[13];
  const float* b2s  = (const float*)d_in[14];
  const float* b2t  = (const float*)d_in[15];
  const float* b3w0 = (const float*)d_in[16];
  const float* b3s0 = (const float*)d_in[17];
  const float* b3t0 = (const float*)d_in[18];
  const float* b3w  = (const float*)d_in[19];
  const float* b3s  = (const float*)d_in[20];
  const float* b3t  = (const float*)d_in[21];
  float* out = (float*)d_out;

  // ws layout (peak ~165MB):
  //  [0, 8HW) floats:      vox cnt (2HW ints) + sums (6HW floats)
  //  [0, 64HW) floats:     s16a / s16b (block1/2 ping-pong); later ppA bf16
  //  [64HW, 192HW) floats: NHWC fp32 canvas (vfe scatter; dead after conv64)
  //  [192HW*4, +387KB):    Wt bf16 (prepacked up front, disjoint from all)
  //  [192HW*4 + 512KB, +9216B): wc64 fp32 conv64 weight table
  float* wsf = (float*)d_ws;
  int* cnt = (int*)wsf;
  float* sums = wsf + (size_t)2 * HW;
  float* s16a = wsf;
  float* s16b = wsf + (size_t)32 * HW;
  float* canv = wsf + (size_t)64 * HW;               // 128HW floats
  __bf16* ppA = (__bf16*)d_ws;                       // + b*64*HW elements
  __bf16* Wt = (__bf16*)((char*)d_ws + (size_t)192 * HW * 4);
  float* wc64 = (float*)((char*)d_ws + (size_t)192 * HW * 4 + 512 * 1024);

  // prepack first: no deps, off the critical path
  prepack<<<765, 256, 0, stream>>>(b3w0, b3w, Wt, b1w0, wc64);

  hipMemsetAsync(cnt, 0, (size_t)8 * HW * sizeof(float), stream);
  hipMemsetAsync(canv, 0, (size_t)128 * HW * sizeof(float), stream);

  count_kernel<<<(Bn * Np + 255) / 256, 256, 0, stream>>>(pts, cnt, sums);
  vfe_kernel<<<(Bn * Np * 64 + 255) / 256, 256, 0, stream>>>(pts, cnt, sums, vw, vs,
                                                             vt, canv);

  const int g2 = (2 * HW + 255) / 256;
  dim3 blk(256);

  // block1: 64->4 (NHWC canvas, LDS halo + scalar weights), 3x(4->4)
  conv64_tile<<<dim3(27 * 62, Bn), dim3(128), 0, stream>>>(canv, wc64, b1s0, b1t0,
                                                           s16a);
  conv3x3<4, 4><<<dim3(g2, 1), blk, 0, stream>>>(s16a, 4 * HW, b1w + 0 * 144,
                                                 b1s + 0, b1t + 0, s16b, 4 * HW,
                                                 2 * HW);
  conv3x3<4, 4><<<dim3(g2, 1), blk, 0, stream>>>(s16b, 4 * HW, b1w + 1 * 144,
                                                 b1s + 4, b1t + 4, s16a, 4 * HW,
                                                 2 * HW);
  conv3x3<4, 4><<<dim3(g2, 1), blk, 0, stream>>>(s16a, 4 * HW, b1w + 2 * 144,
                                                 b1s + 8, b1t + 8, out, 84 * HW,
                                                 2 * HW);

  // block2: 4->16, 4x(16->16), then DUAL last layer; x2 -> out ch4..19 + n16
  __bf16* n16 = (__bf16*)(out + (size_t)20 * HW);  // out ch20..83 reuse (dead)
  conv3x3<4, 16><<<dim3(g2, 1), blk, 0, stream>>>(out, 84 * HW, b2w0, b2s0, b2t0,
                                                  s16a, 16 * HW, 2 * HW);
  conv3x3<16, 16><<<dim3(g2, 1), blk, 0, stream>>>(s16a, 16 * HW, b2w + 0 * 2304,
                                                   b2s + 0, b2t + 0, s16b, 16 * HW,
                                                   2 * HW);
  conv3x3<16, 16><<<dim3(g2, 1), blk, 0, stream>>>(s16b, 16 * HW, b2w + 1 * 2304,
                                                   b2s + 16, b2t + 16, s16a, 16 * HW,
                                                   2 * HW);
  conv3x3<16, 16><<<dim3(g2, 1), blk, 0, stream>>>(s16a, 16 * HW, b2w + 2 * 2304,
                                                   b2s + 32, b2t + 32, s16b, 16 * HW,
                                                   2 * HW);
  conv3x3<16, 16><<<dim3(g2, 1), blk, 0, stream>>>(s16b, 16 * HW, b2w + 3 * 2304,
                                                   b2s + 48, b2t + 48, s16a, 16 * HW,
                                                   2 * HW);
  conv16_dual<<<g2, blk, 0, stream>>>(s16a, b2w + 4 * 2304, b2s + 64, b2t + 64,
                                      out + 4 * HW, n16);

  // block3 via MFMA, BOTH batches per dispatch (grid.y = Bn). R5 chain.
  const size_t canv_s = (size_t)84 * HW * 2;  // bf16 elems per batch
  const size_t ppa_s = (size_t)64 * HW;
  dim3 mg(31 * 27, Bn);  // 16x16-pixel tiles x batches
  mconv<16, false><<<mg, blk, 0, stream>>>(n16, canv_s, Wt, b3s0, b3t0, ppA, ppa_s,
                                           nullptr, 0);
  mconv<64, false><<<mg, blk, 0, stream>>>(ppA, ppa_s, Wt + 9216 + 0 * 36864,
                                           b3s + 0, b3t + 0, n16, canv_s, nullptr,
                                           0);
  mconv<64, false><<<mg, blk, 0, stream>>>(n16, canv_s, Wt + 9216 + 1 * 36864,
                                           b3s + 64, b3t + 64, ppA, ppa_s, nullptr,
                                           0);
  mconv<64, false><<<mg, blk, 0, stream>>>(ppA, ppa_s, Wt + 9216 + 2 * 36864,
                                           b3s + 128, b3t + 128, n16, canv_s,
                                           nullptr, 0);
  mconv<64, false><<<mg, blk, 0, stream>>>(n16, canv_s, Wt + 9216 + 3 * 36864,
                                           b3s + 192, b3t + 192, ppA, ppa_s,
                                           nullptr, 0);
  mconv<64, true><<<mg, blk, 0, stream>>>(ppA, ppa_s, Wt + 9216 + 4 * 36864,
                                          b3s + 256, b3t + 256, nullptr, 0,
                                          out + (size_t)20 * HW, (size_t)84 * HW);
}

// Round 15
// 776.698 us; speedup vs baseline: 1.3098x; 1.0603x over previous
//
#include <hip/hip_runtime.h>
#include <math.h>

static constexpr int H = 496, W = 432, Bn = 2, Np = 16000;
static constexpr int HW = H * W;  // 214272

typedef __bf16 bf16x8 __attribute__((ext_vector_type(8)));
typedef float f32x16 __attribute__((ext_vector_type(16)));

// Gold-matching binning (R7-verified): multiply by f32-rounded reciprocal
// (RN_f32(1/0.16f) == 6.25f). DO NOT change to division.
__device__ inline void bin_xy(float px, float py, int& ix, int& iy) {
  ix = (int)floorf(px * 6.25f);
  iy = (int)floorf((py + 39.68f) * 6.25f);
  ix = min(max(ix, 0), W - 1);
  iy = min(max(iy, 0), H - 1);
}

// ---------------- Voxelization pass 1 ----------------
__global__ __launch_bounds__(256)
void count_kernel(const float* __restrict__ pts, int* __restrict__ cnt,
                  float* __restrict__ sums) {
  int p = blockIdx.x * blockDim.x + threadIdx.x;
  if (p >= Bn * Np) return;
  float px = pts[p * 4 + 0], py = pts[p * 4 + 1], pz = pts[p * 4 + 2];
  int b = p / Np;
  int ix, iy;
  bin_xy(px, py, ix, iy);
  int gid = b * HW + iy * W + ix;
  atomicAdd(&cnt[gid], 1);
  atomicAdd(&sums[3 * gid + 0], px);
  atomicAdd(&sums[3 * gid + 1], py);
  atomicAdd(&sums[3 * gid + 2], pz);
}

// ---------------- Voxelization pass 2: VFE + atomicMax scatter ----------------
// NHWC fp32 canvas in ws — lane o -> consecutive float: a wave's 64 atomics
// hit 4 cache lines instead of 64 (R8-verified win).
__global__ __launch_bounds__(256)
void vfe_kernel(const float* __restrict__ pts, const int* __restrict__ cnt,
                const float* __restrict__ sums, const float* __restrict__ vw,
                const float* __restrict__ vs, const float* __restrict__ vt,
                float* __restrict__ canv) {
  int tid = blockIdx.x * blockDim.x + threadIdx.x;
  if (tid >= Bn * Np * 64) return;
  int o = tid & 63;
  int p = tid >> 6;
  int b = p / Np;
  float px = pts[p * 4 + 0], py = pts[p * 4 + 1];
  float pz = pts[p * 4 + 2], pr = pts[p * 4 + 3];
  int ix, iy;
  bin_xy(px, py, ix, iy);
  int gid = b * HW + iy * W + ix;
  int n = cnt[gid];
  float denom = (float)max(n, 1);
  float mx = sums[3 * gid + 0] / denom;
  float my = sums[3 * gid + 1] / denom;
  float mz = sums[3 * gid + 2] / denom;
  float cx = (float)ix * 0.16f + 0.08f;
  float cy = (float)iy * 0.16f + (0.08f - 39.68f);
  float f[10] = {px, py, pz, pr, px - mx, py - my, pz - mz,
                 px - cx, py - cy, pz + 1.0f};
  const float* wr = vw + o * 10;
  float d = 0.f;
#pragma unroll
  for (int c = 0; c < 10; c++) d += f[c] * wr[c];
  float val = d * vs[o] + vt[o];
  val = fmaxf(val, 0.f);
  if (n < 32) val = fmaxf(val, fmaxf(vt[o], 0.f));
  unsigned int* dst = (unsigned int*)(canv + (size_t)gid * 64 + o);
  atomicMax(dst, __float_as_uint(val));
}

// ---------------- block1 layer0: 64->4 conv, LDS halo + scalar weights -------
// R14/R15: R11/R13 was latency-bound at 1.5 waves/SIMD (occ 14%, VALUBusy 27%)
// — 46KB halo LDS capped residency. Fix WITHOUT sharing pixels across waves
// (R12's mistake, duplicated LDS reads): 16x16-px tile, 256 thr (1 thr/pixel,
// exclusive), halo staged in TWO ci-chunks of 32 (18x18x32 fp32 = 41.5KB) ->
// 3 blocks/CU x 4 waves = 3 waves/SIMD (2x occupancy). Weights stay wave-
// uniform from the [tp][ci][co0..3] table (scalar pipe). Swizzle slot=
// (c4+hp)&7 on 128B rows: bank-start 4*slot, 8 lanes/bank-group over the 8
// b128 phases -> conflict floor. Chunk-outer summation reorders fp32 adds
// (~1e-6 noise; threshold 4.7e-2, bf16 floor 3.9e-3 dominates).
__global__ __launch_bounds__(256, 3)
void conv64_tile(const float* __restrict__ canv, const float* __restrict__ wc,
                 const float* __restrict__ s, const float* __restrict__ t,
                 float* __restrict__ out4) {
  __shared__ __align__(16) float hl[324 * 32];  // 18x18 px x 32 ch = 41,472 B

  const int tid = threadIdx.x;  // = pixel within 16x16 tile
  const int b = blockIdx.y;
  const int ty = blockIdx.x / 27, tx = blockIdx.x - ty * 27;
  const int y0 = ty * 16, x0 = tx * 16;
  const float* cb = canv + (size_t)b * HW * 64;
  const int ly = tid >> 4, lx = tid & 15;

  float a0 = 0.f, a1 = 0.f, a2 = 0.f, a3 = 0.f;

  for (int ch = 0; ch < 2; ++ch) {
    if (ch) __syncthreads();  // chunk-0 reads complete before restage
    // stage halo 18x18 px x 32 ch; c4-block stored at slot (c4+hp)&7
    for (int q = tid; q < 324 * 8; q += 256) {
      int hp = q >> 3, c4 = q & 7;
      int hy = hp / 18, hx = hp - hy * 18;
      int gy = y0 - 1 + hy, gx = x0 - 1 + hx;
      float4 v = {0.f, 0.f, 0.f, 0.f};
      if ((unsigned)gy < (unsigned)H && (unsigned)gx < (unsigned)W)
        v = *(const float4*)(cb + (size_t)(gy * W + gx) * 64 + ch * 32 + c4 * 4);
      *(float4*)(hl + hp * 32 + ((c4 + hp) & 7) * 4) = v;
    }
    __syncthreads();

#pragma unroll 1
    for (int tp = 0; tp < 9; ++tp) {
      const int hp = (ly + tp / 3) * 18 + lx + tp % 3;
      const float* hb = hl + hp * 32;
      const float* wt_ = wc + tp * 256 + ch * 128;  // [ci][co0..3], wave-uniform
#pragma unroll 4
      for (int c4 = 0; c4 < 8; ++c4) {
        float4 v = *(const float4*)(hb + ((c4 + hp) & 7) * 4);
        const float* wp = wt_ + c4 * 16;
        float4 wq0 = *(const float4*)(wp + 0);
        float4 wq1 = *(const float4*)(wp + 4);
        float4 wq2 = *(const float4*)(wp + 8);
        float4 wq3 = *(const float4*)(wp + 12);
        a0 = fmaf(v.x, wq0.x, a0);
        a1 = fmaf(v.x, wq0.y, a1);
        a2 = fmaf(v.x, wq0.z, a2);
        a3 = fmaf(v.x, wq0.w, a3);
        a0 = fmaf(v.y, wq1.x, a0);
        a1 = fmaf(v.y, wq1.y, a1);
        a2 = fmaf(v.y, wq1.z, a2);
        a3 = fmaf(v.y, wq1.w, a3);
        a0 = fmaf(v.z, wq2.x, a0);
        a1 = fmaf(v.z, wq2.y, a1);
        a2 = fmaf(v.z, wq2.z, a2);
        a3 = fmaf(v.z, wq2.w, a3);
        a0 = fmaf(v.w, wq3.x, a0);
        a1 = fmaf(v.w, wq3.y, a1);
        a2 = fmaf(v.w, wq3.z, a2);
        a3 = fmaf(v.w, wq3.w, a3);
      }
    }
  }
  float* ob = out4 + (size_t)b * 4 * HW + (size_t)(y0 + ly) * W + x0 + lx;
  ob[0 * HW] = fmaxf(a0 * s[0] + t[0], 0.f);
  ob[1 * HW] = fmaxf(a1 * s[1] + t[1], 0.f);
  ob[2 * HW] = fmaxf(a2 * s[2] + t[2], 0.f);
  ob[3 * HW] = fmaxf(a3 * s[3] + t[3], 0.f);
}

// ---------------- fp32 direct 3x3 conv (blocks 1 & 2) ----------------
template <int CI, int COT>
__global__ __launch_bounds__(256)
void conv3x3(const float* __restrict__ in, int in_bs, const float* __restrict__ w,
             const float* __restrict__ s, const float* __restrict__ t,
             float* __restrict__ out, int out_bs, int npix) {
  int pix = blockIdx.x * blockDim.x + threadIdx.x;
  if (pix >= npix) return;
  int b = pix / HW;
  int rem = pix - b * HW;
  int y = rem / W;
  int x = rem - y * W;
  int co0 = blockIdx.y * COT;
  const float* inb = in + (size_t)b * in_bs;

  int offs[9];
  bool okm[9];
#pragma unroll
  for (int ky = 0; ky < 3; ky++) {
    int yy = y + ky - 1;
    bool yok = (unsigned)yy < (unsigned)H;
#pragma unroll
    for (int kx = 0; kx < 3; kx++) {
      int xx = x + kx - 1;
      okm[ky * 3 + kx] = yok && ((unsigned)xx < (unsigned)W);
      offs[ky * 3 + kx] = yy * W + xx;
    }
  }
  float acc[COT];
#pragma unroll
  for (int i = 0; i < COT; i++) acc[i] = 0.f;
  for (int ci = 0; ci < CI; ci++) {
    const float* ip = inb + (size_t)ci * HW;
    float iv[9];
#pragma unroll
    for (int k = 0; k < 9; k++) iv[k] = okm[k] ? ip[offs[k]] : 0.f;
    const float* wp = w + ((size_t)co0 * CI + ci) * 9;
#pragma unroll
    for (int cg_ = 0; cg_ < COT; cg_++) {
      const float* wc_ = wp + (size_t)cg_ * CI * 9;
#pragma unroll
      for (int k = 0; k < 9; k++) acc[cg_] = fmaf(iv[k], wc_[k], acc[cg_]);
    }
  }
  float* ob = out + (size_t)b * out_bs + (size_t)rem;
#pragma unroll
  for (int cg_ = 0; cg_ < COT; cg_++) {
    float v = acc[cg_] * s[co0 + cg_] + t[co0 + cg_];
    ob[(size_t)(co0 + cg_) * HW] = fmaxf(v, 0.f);
  }
}

// ---------------- block2 last layer: 16->16 conv, DUAL output ---------------
// Writes x2 as NCHW fp32 (checked output, ch4..19) AND the same values as
// NHWC bf16 (block3 L0 input) — replaces the separate cvt dispatch.
__global__ __launch_bounds__(256)
void conv16_dual(const float* __restrict__ in, const float* __restrict__ w,
                 const float* __restrict__ s, const float* __restrict__ t,
                 float* __restrict__ out, __bf16* __restrict__ n16) {
  int pix = blockIdx.x * blockDim.x + threadIdx.x;
  if (pix >= Bn * HW) return;
  int b = pix / HW;
  int rem = pix - b * HW;
  int y = rem / W;
  int x = rem - y * W;
  const float* inb = in + (size_t)b * 16 * HW;

  int offs[9];
  bool okm[9];
#pragma unroll
  for (int ky = 0; ky < 3; ky++) {
    int yy = y + ky - 1;
    bool yok = (unsigned)yy < (unsigned)H;
#pragma unroll
    for (int kx = 0; kx < 3; kx++) {
      int xx = x + kx - 1;
      okm[ky * 3 + kx] = yok && ((unsigned)xx < (unsigned)W);
      offs[ky * 3 + kx] = yy * W + xx;
    }
  }
  float acc[16];
#pragma unroll
  for (int i = 0; i < 16; i++) acc[i] = 0.f;
  for (int ci = 0; ci < 16; ci++) {
    const float* ip = inb + (size_t)ci * HW;
    float iv[9];
#pragma unroll
    for (int k = 0; k < 9; k++) iv[k] = okm[k] ? ip[offs[k]] : 0.f;
    const float* wp = w + (size_t)ci * 9;
#pragma unroll
    for (int cg_ = 0; cg_ < 16; cg_++) {
      const float* wc_ = wp + (size_t)cg_ * 16 * 9;
#pragma unroll
      for (int k = 0; k < 9; k++) acc[cg_] = fmaf(iv[k], wc_[k], acc[cg_]);
    }
  }
  float* ob = out + (size_t)b * 84 * HW + (size_t)rem;
  __bf16 vv[16];
#pragma unroll
  for (int cg_ = 0; cg_ < 16; cg_++) {
    float v = fmaxf(acc[cg_] * s[cg_] + t[cg_], 0.f);
    ob[(size_t)cg_ * HW] = v;
    vv[cg_] = (__bf16)v;
  }
  __bf16* nb = n16 + (size_t)b * (84 * HW * 2) + (size_t)rem * 16;
  *(bf16x8*)nb = *(bf16x8*)vv;
  *(bf16x8*)(nb + 8) = *(bf16x8*)(vv + 8);
}

// ---------------- weight prepack: block3 MFMA + conv64 scalar table ----------
// Wt: fragment-ordered bf16 (1KB contiguous per wave B-frag load).
// wc64: conv64 fp32 table [tp][ci][co0..3] -> wave-uniform float4 rows.
__global__ __launch_bounds__(256)
void prepack(const float* __restrict__ w0, const float* __restrict__ ws,
             __bf16* __restrict__ wt, const float* __restrict__ w1,
             float* __restrict__ wc) {
  int idx = blockIdx.x * 256 + threadIdx.x;
  const int E0 = 64 * 144, EN = 64 * 576;
  if (idx < E0) {
    // layer0 CI=16: block = tp*2+nt (KC=1)
    int blk = idx >> 9, rem = idx & 511;
    int tp = blk >> 1, nt = blk & 1;
    int co = nt * 32 + (rem >> 4);
    int ci = rem & 15;  // = khalf*8 + e
    int ky = tp / 3, kx = tp - ky * 3;
    wt[idx] = (__bf16)w0[((co * 16 + ci) * 3 + ky) * 3 + kx];
  } else if (idx < E0 + 5 * EN) {
    int j = idx - E0;
    int n = j / EN, rr = j - n * EN;
    // CI=64: block = (tp*4+kc)*2+nt
    int blk = rr >> 9, rem = rr & 511;
    int tpkc = blk >> 1, nt = blk & 1;
    int tp = tpkc >> 2, kc = tpkc & 3;
    int co = nt * 32 + (rem >> 4);
    int ci = kc * 16 + (rem & 15);
    int ky = tp / 3, kx = tp - ky * 3;
    wt[idx] = (__bf16)ws[n * 36864 + ((co * 64 + ci) * 3 + ky) * 3 + kx];
  } else if (idx < E0 + 5 * EN + 2304) {
    int e = idx - E0 - 5 * EN;  // e = tp*256 + ci*4 + co
    int tp = e >> 8, r = e & 255;
    int ci = r >> 2, co = r & 3;
    wc[e] = w1[co * 576 + ci * 9 + tp];  // b1w0 OIHW (co,ci,ky,kx)
  }
}

// ---------------- MFMA implicit-GEMM 3x3 conv, NHWC bf16 in, BOTH batches ------
// R5/R11-verified kernel (do not restructure: R2 pipeline, R5 occupancy, R12
// kc-outer LDS-weights all neutral-to-negative). wg = 256 thr (4 waves), tile
// 16x16 px x 64 co. Halo (18x18 x CI) staged once in LDS. Wave wv owns 64 px
// as 2 m-tiles x 2 n-tiles (4 f32x16 accs). grid = (837, Bn).
// FINAL: BN+ReLU then LDS-transpose (two 128-px chunks) -> coalesced NCHW fp32.
template <int CI, bool FINAL>
__global__ __launch_bounds__(256, 3)
void mconv(const __bf16* __restrict__ in, size_t in_bstride,
           const __bf16* __restrict__ wt, const float* __restrict__ s,
           const float* __restrict__ t, __bf16* __restrict__ outb,
           size_t outb_bstride, float* __restrict__ outf, size_t outf_bstride) {
  constexpr int KC = CI / 16;
  constexpr int PADW = (CI == 64) ? 72 : 24;  // bf16 per-pixel stride; 16B-aligned
  constexpr int HALO_B = 324 * PADW * 2;      // 18x18 pixels
  constexpr int TRAN_B = FINAL ? 128 * 66 * 4 : 0;
  constexpr int SMEM_B = HALO_B > TRAN_B ? HALO_B : TRAN_B;  // 46656 for CI=64
  __shared__ __align__(16) char smem[SMEM_B];
  __bf16* hl = (__bf16*)smem;

  const int tid = threadIdx.x;
  const int bz = blockIdx.y;
  const int ty = blockIdx.x / 27, tx = blockIdx.x - ty * 27;
  const int y0 = ty * 16, x0 = tx * 16;
  in += (size_t)bz * in_bstride;

  // stage halo: 18x18 pixels x CI channels (zeros outside image)
  constexpr int NCH = CI / 8;
  constexpr int TOT = 324 * NCH;
  for (int q = tid; q < TOT; q += 256) {
    int hp = q / NCH, c8 = q - hp * NCH;
    int hy = hp / 18, hx = hp - hy * 18;
    int gy = y0 - 1 + hy, gx = x0 - 1 + hx;
    int4 v = {0, 0, 0, 0};
    if ((unsigned)gy < (unsigned)H && (unsigned)gx < (unsigned)W)
      v = *(const int4*)(in + (size_t)(gy * W + gx) * CI + c8 * 8);
    *(int4*)(hl + hp * PADW + c8 * 8) = v;
  }
  __syncthreads();

  const int lane = tid & 63;
  const int wv = tid >> 6;
  const int col = lane & 31, half = lane >> 5;
  const int ly0 = 4 * wv + (col >> 4);  // A: m = col -> pixel row of m-tile 0
  const int lx = col & 15;

  f32x16 z = {0.f, 0.f, 0.f, 0.f, 0.f, 0.f, 0.f, 0.f,
              0.f, 0.f, 0.f, 0.f, 0.f, 0.f, 0.f, 0.f};
  f32x16 a00 = z, a01 = z, a10 = z, a11 = z;  // [mtile][ntile]

  const int laneoff = col * 16 + half * 8;
  const __bf16* wbase = wt + laneoff;

#pragma unroll
  for (int tp = 0; tp < 9; ++tp) {
    const __bf16* a0r = hl + ((ly0 + tp / 3) * 18 + lx + tp % 3) * PADW + half * 8;
    const __bf16* a1r = a0r + 2 * 18 * PADW;  // m-tile 1: +2 pixel rows
    const __bf16* bb = wbase + ((tp * KC) << 10);
#pragma unroll
    for (int kc = 0; kc < KC; ++kc) {
      bf16x8 af0 = *(const bf16x8*)(a0r + kc * 16);
      bf16x8 af1 = *(const bf16x8*)(a1r + kc * 16);
      bf16x8 b0 = *(const bf16x8*)(bb + (kc << 10));
      bf16x8 b1 = *(const bf16x8*)(bb + (kc << 10) + 512);
      a00 = __builtin_amdgcn_mfma_f32_32x32x16_bf16(af0, b0, a00, 0, 0, 0);
      a01 = __builtin_amdgcn_mfma_f32_32x32x16_bf16(af0, b1, a01, 0, 0, 0);
      a10 = __builtin_amdgcn_mfma_f32_32x32x16_bf16(af1, b0, a10, 0, 0, 0);
      a11 = __builtin_amdgcn_mfma_f32_32x32x16_bf16(af1, b1, a11, 0, 0, 0);
    }
  }

  float s0 = s[col], t0v = t[col], s1 = s[col + 32], t1v = t[col + 32];
  if constexpr (!FINAL) {
    __bf16* ob = outb + (size_t)bz * outb_bstride;
#pragma unroll
    for (int r = 0; r < 16; ++r) {
      int row = (r & 3) + 8 * (r >> 2) + 4 * half;  // verified C/D map (m74/m101)
      int py = y0 + 4 * wv + (row >> 4);
      int px = x0 + (row & 15);
      size_t gp0 = (size_t)py * W + px;
      size_t gp1 = gp0 + (size_t)2 * W;  // m-tile 1
      ob[gp0 * 64 + col] = (__bf16)fmaxf(a00[r] * s0 + t0v, 0.f);
      ob[gp0 * 64 + col + 32] = (__bf16)fmaxf(a01[r] * s1 + t1v, 0.f);
      ob[gp1 * 64 + col] = (__bf16)fmaxf(a10[r] * s0 + t0v, 0.f);
      ob[gp1 * 64 + col + 32] = (__bf16)fmaxf(a11[r] * s1 + t1v, 0.f);
    }
  } else {
    float* of = outf + (size_t)bz * outf_bstride;
    float* tl = (float*)smem;
    // two 128-pixel chunks (waves {0,1} then {2,3}) so tl fits under halo size
    for (int h = 0; h < 2; ++h) {
      __syncthreads();  // h=0: halo reads done; h=1: chunk-0 stores done
      if ((wv >> 1) == h) {
        int wl_ = wv & 1;
#pragma unroll
        for (int r = 0; r < 16; ++r) {
          int row = (r & 3) + 8 * (r >> 2) + 4 * half;
          int lp0 = (4 * wl_ + (row >> 4)) * 16 + (row & 15);
          int lp1 = lp0 + 32;  // +2 pixel rows
          tl[lp0 * 66 + col] = fmaxf(a00[r] * s0 + t0v, 0.f);
          tl[lp0 * 66 + col + 32] = fmaxf(a01[r] * s1 + t1v, 0.f);
          tl[lp1 * 66 + col] = fmaxf(a10[r] * s0 + t0v, 0.f);
          tl[lp1 * 66 + col + 32] = fmaxf(a11[r] * s1 + t1v, 0.f);
        }
      }
      __syncthreads();
      for (int e = tid; e < 128 * 64; e += 256) {
        int co = e >> 7, mtl = e & 127;
        of[(size_t)co * HW + (size_t)(y0 + h * 8 + (mtl >> 4)) * W +
           (x0 + (mtl & 15))] = tl[mtl * 66 + co];
      }
    }
  }
}

extern "C" void kernel_launch(void* const* d_in, const int* in_sizes, int n_in,
                              void* d_out, int out_size, void* d_ws, size_t ws_size,
                              hipStream_t stream) {
  const float* pts  = (const float*)d_in[0];
  const float* vw   = (const float*)d_in[1];
  const float* vs   = (const float*)d_in[2];
  const float* vt   = (const float*)d_in[3];
  const float* b1w0 = (const float*)d_in[4];
  const float* b1s0 = (const float*)d_in[5];
  const float* b1t0 = (const float*)d_in[6];
  const float* b1w  = (const float*)d_in[7];
  const float* b1s  = (const float*)d_in[8];
  const float* b1t  = (const float*)d_in[9];
  const float* b2w0 = (const float*)d_in[10];
  const float* b2s0 = (const float*)d_in[11];
  const float* b2t0 = (const float*)d_in[12];
  const float* b2w  = (const float*)d_in[13];
  const float* b2s  = (const float*)d_in[14];
  const float* b2t  = (const float*)d_in[15];
  const float* b3w0 = (const float*)d_in[16];
  const float* b3s0 = (const float*)d_in[17];
  const float* b3t0 = (const float*)d_in[18];
  const float* b3w  = (const float*)d_in[19];
  const float* b3s  = (const float*)d_in[20];
  const float* b3t  = (const float*)d_in[21];
  float* out = (float*)d_out;

  // ws layout (peak ~165MB):
  //  [0, 8HW) floats:      vox cnt (2HW ints) + sums (6HW floats)
  //  [0, 64HW) floats:     s16a / s16b (block1/2 ping-pong); later ppA bf16
  //  [64HW, 192HW) floats: NHWC fp32 canvas (vfe scatter; dead after conv64)
  //  [192HW*4, +387KB):    Wt bf16 (prepacked up front, disjoint from all)
  //  [192HW*4 + 512KB, +9216B): wc64 fp32 conv64 weight table
  float* wsf = (float*)d_ws;
  int* cnt = (int*)wsf;
  float* sums = wsf + (size_t)2 * HW;
  float* s16a = wsf;
  float* s16b = wsf + (size_t)32 * HW;
  float* canv = wsf + (size_t)64 * HW;               // 128HW floats
  __bf16* ppA = (__bf16*)d_ws;                       // + b*64*HW elements
  __bf16* Wt = (__bf16*)((char*)d_ws + (size_t)192 * HW * 4);
  float* wc64 = (float*)((char*)d_ws + (size_t)192 * HW * 4 + 512 * 1024);

  // prepack first: no deps, off the critical path
  prepack<<<765, 256, 0, stream>>>(b3w0, b3w, Wt, b1w0, wc64);

  hipMemsetAsync(cnt, 0, (size_t)8 * HW * sizeof(float), stream);
  hipMemsetAsync(canv, 0, (size_t)128 * HW * sizeof(float), stream);

  count_kernel<<<(Bn * Np + 255) / 256, 256, 0, stream>>>(pts, cnt, sums);
  vfe_kernel<<<(Bn * Np * 64 + 255) / 256, 256, 0, stream>>>(pts, cnt, sums, vw, vs,
                                                             vt, canv);

  const int g2 = (2 * HW + 255) / 256;
  dim3 blk(256);

  // block1: 64->4 (NHWC canvas, LDS halo chunked + scalar weights), 3x(4->4)
  conv64_tile<<<dim3(27 * 31, Bn), blk, 0, stream>>>(canv, wc64, b1s0, b1t0, s16a);
  conv3x3<4, 4><<<dim3(g2, 1), blk, 0, stream>>>(s16a, 4 * HW, b1w + 0 * 144,
                                                 b1s + 0, b1t + 0, s16b, 4 * HW,
                                                 2 * HW);
  conv3x3<4, 4><<<dim3(g2, 1), blk, 0, stream>>>(s16b, 4 * HW, b1w + 1 * 144,
                                                 b1s + 4, b1t + 4, s16a, 4 * HW,
                                                 2 * HW);
  conv3x3<4, 4><<<dim3(g2, 1), blk, 0, stream>>>(s16a, 4 * HW, b1w + 2 * 144,
                                                 b1s + 8, b1t + 8, out, 84 * HW,
                                                 2 * HW);

  // block2: 4->16, 4x(16->16), then DUAL last layer; x2 -> out ch4..19 + n16
  __bf16* n16 = (__bf16*)(out + (size_t)20 * HW);  // out ch20..83 reuse (dead)
  conv3x3<4, 16><<<dim3(g2, 1), blk, 0, stream>>>(out, 84 * HW, b2w0, b2s0, b2t0,
                                                  s16a, 16 * HW, 2 * HW);
  conv3x3<16, 16><<<dim3(g2, 1), blk, 0, stream>>>(s16a, 16 * HW, b2w + 0 * 2304,
                                                   b2s + 0, b2t + 0, s16b, 16 * HW,
                                                   2 * HW);
  conv3x3<16, 16><<<dim3(g2, 1), blk, 0, stream>>>(s16b, 16 * HW, b2w + 1 * 2304,
                                                   b2s + 16, b2t + 16, s16a, 16 * HW,
                                                   2 * HW);
  conv3x3<16, 16><<<dim3(g2, 1), blk, 0, stream>>>(s16a, 16 * HW, b2w + 2 * 2304,
                                                   b2s + 32, b2t + 32, s16b, 16 * HW,
                                                   2 * HW);
  conv3x3<16, 16><<<dim3(g2, 1), blk, 0, stream>>>(s16b, 16 * HW, b2w + 3 * 2304,
                                                   b2s + 48, b2t + 48, s16a, 16 * HW,
                                                   2 * HW);
  conv16_dual<<<g2, blk, 0, stream>>>(s16a, b2w + 4 * 2304, b2s + 64, b2t + 64,
                                      out + 4 * HW, n16);

  // block3 via MFMA, BOTH batches per dispatch (grid.y = Bn). R5 chain.
  const size_t canv_s = (size_t)84 * HW * 2;  // bf16 elems per batch
  const size_t ppa_s = (size_t)64 * HW;
  dim3 mg(31 * 27, Bn);  // 16x16-pixel tiles x batches
  mconv<16, false><<<mg, blk, 0, stream>>>(n16, canv_s, Wt, b3s0, b3t0, ppA, ppa_s,
                                           nullptr, 0);
  mconv<64, false><<<mg, blk, 0, stream>>>(ppA, ppa_s, Wt + 9216 + 0 * 36864,
                                           b3s + 0, b3t + 0, n16, canv_s, nullptr,
                                           0);
  mconv<64, false><<<mg, blk, 0, stream>>>(n16, canv_s, Wt + 9216 + 1 * 36864,
                                           b3s + 64, b3t + 64, ppA, ppa_s, nullptr,
                                           0);
  mconv<64, false><<<mg, blk, 0, stream>>>(ppA, ppa_s, Wt + 9216 + 2 * 36864,
                                           b3s + 128, b3t + 128, n16, canv_s,
                                           nullptr, 0);
  mconv<64, false><<<mg, blk, 0, stream>>>(n16, canv_s, Wt + 9216 + 3 * 36864,
                                           b3s + 192, b3t + 192, ppA, ppa_s,
                                           nullptr, 0);
  mconv<64, true><<<mg, blk, 0, stream>>>(ppA, ppa_s, Wt + 9216 + 4 * 36864,
                                          b3s + 256, b3t + 256, nullptr, 0,
                                          out + (size_t)20 * HW, (size_t)84 * HW);
}